// Round 1
// baseline (3254.198 us; speedup 1.0000x reference)
//
#include <hip/hip_runtime.h>
#include <hip/hip_bf16.h>
#include <math.h>

#define IN_CH   256
#define OUT_CH  256
#define STATE   384
#define OUT_SEQ 32
#define B_SZ    8
#define SEQ     512
#define M_ROWS  (B_SZ*SEQ)   // 4096

// ---------------- workspace layout (in floats) ----------------
// U  : [4096][768]  interleaved (re,im) per state     -> 3,145,728
// Z  : [4096][768]  hs interleaved                     -> 3,145,728
// XA : [4096][256]                                     -> 1,048,576
// XB : [4096][256]                                     -> 1,048,576
// BgT: [256][768]   BgT[c][2n+f] = gamma_n * B_{re/im}[n][c]
// Wc : [768][256]   Wc[2n][o]=C_re[o][n], Wc[2n+1][o]=-C_im[o][n]
// Wd : [256][256]   Wd[c][o] = D[o][c]
// lam: [768]        (lre,lim) interleaved per n
// Hc : [8][768]     carried state, interleaved
static const size_t OFF_U   = 0;
static const size_t OFF_Z   = OFF_U   + (size_t)M_ROWS*768;
static const size_t OFF_XA  = OFF_Z   + (size_t)M_ROWS*768;
static const size_t OFF_XB  = OFF_XA  + (size_t)M_ROWS*256;
static const size_t OFF_BGT = OFF_XB  + (size_t)M_ROWS*256;
static const size_t OFF_WC  = OFF_BGT + 256*768;
static const size_t OFF_WD  = OFF_WC  + 768*256;
static const size_t OFF_LAM = OFF_WD  + 256*256;
static const size_t OFF_HC  = OFF_LAM + 768;
// total ~9.0 M floats = ~36 MB

// ---------------- prep kernels ----------------
__global__ void prep_lam_hc(const float* __restrict__ nu_log,
                            const float* __restrict__ th_log,
                            float* __restrict__ lam, float* __restrict__ hc) {
    int n = threadIdx.x;
    if (n < STATE) {
        float lm = expf(-expf(nu_log[n]));
        float th = expf(th_log[n]);
        lam[2*n]   = lm * cosf(th);
        lam[2*n+1] = lm * sinf(th);
    }
    for (int i = threadIdx.x; i < B_SZ*2*STATE; i += blockDim.x) hc[i] = 0.f;
}

__global__ void prep_bgt(const float* __restrict__ B_re, const float* __restrict__ B_im,
                         const float* __restrict__ gamma_log, float* __restrict__ BgT) {
    int idx = blockIdx.x*blockDim.x + threadIdx.x;   // < 256*768
    int c = idx / 768, jj = idx % 768;
    int n = jj >> 1;
    float g = expf(gamma_log[n]);
    float v = (jj & 1) ? B_im[n*IN_CH + c] : B_re[n*IN_CH + c];
    BgT[idx] = g * v;
}

__global__ void prep_w(const float* __restrict__ C_re, const float* __restrict__ C_im,
                       const float* __restrict__ D,
                       float* __restrict__ Wc, float* __restrict__ Wd) {
    int idx = blockIdx.x*blockDim.x + threadIdx.x;   // < 768*256 + 256*256
    if (idx < 768*256) {
        int k = idx >> 8, o = idx & 255, n = k >> 1;
        Wc[idx] = (k & 1) ? -C_im[o*STATE + n] : C_re[o*STATE + n];
    } else {
        int j = idx - 768*256;
        int c = j >> 8, o = j & 255;
        Wd[j] = D[o*IN_CH + c];
    }
}

__global__ void copy_x(const float* __restrict__ x, float* __restrict__ XA) {
    int idx = blockIdx.x*blockDim.x + threadIdx.x;   // < 262144 float4s
    ((float4*)XA)[idx] = ((const float4*)x)[idx];
}

// ---------------- scan kernel ----------------
// one thread per (b,n); 48 blocks x 64 threads; 16-deep register prefetch
#define PF 16
__global__ __launch_bounds__(64)
void scan_k(const float* __restrict__ Uf, float* __restrict__ Zf,
            const float* __restrict__ lam, float* __restrict__ Hc) {
    int b = blockIdx.x / 6, g = blockIdx.x % 6;
    int n = g*64 + threadIdx.x;
    float lre = lam[2*n], lim = lam[2*n+1];
    float hre = Hc[b*768 + 2*n], him = Hc[b*768 + 2*n + 1];
    const float2* U2 = (const float2*)Uf + (size_t)b*SEQ*STATE + n;
    float2*       Z2 = (float2*)Zf       + (size_t)b*SEQ*STATE + n;
    float2 buf[PF];
#pragma unroll
    for (int p = 0; p < PF; ++p) buf[p] = U2[(size_t)p*STATE];
    for (int s0 = 0; s0 < SEQ; s0 += PF) {
#pragma unroll
        for (int p = 0; p < PF; ++p) {
            int s = s0 + p;
            float ur = buf[p].x, ui = buf[p].y;
            if (s + PF < SEQ) buf[p] = U2[(size_t)(s+PF)*STATE];
            float nr = fmaf(lre, hre, fmaf(-lim, him, ur));
            float ni = fmaf(lre, him, fmaf( lim, hre, ui));
            hre = nr; him = ni;
            Z2[(size_t)s*STATE] = make_float2(nr, ni);
        }
    }
    Hc[b*768 + 2*n] = hre; Hc[b*768 + 2*n + 1] = him;
}

// ---------------- GEMM: C[M][N] = A[M][K]*B[K][N] (+ A2[M][K2]*B2[K2][N]) ----------------
// 256 threads (16x16); thread computes TM x 4 outputs. BK = 32. All dims divide evenly.
template<int BM, int TM, bool HAS2, bool WRITE_OUT>
__global__ __launch_bounds__(256)
void gemm_f32(const float* __restrict__ A,  const float* __restrict__ B,  int K,
              const float* __restrict__ A2, const float* __restrict__ B2, int K2,
              float* __restrict__ C, int N,
              float* __restrict__ outp, int iter) {
    constexpr int BN = 64, BK = 32;
    __shared__ float As[BK][BM + 4];
    __shared__ float Bs[BK][BN];
    int tid = threadIdx.x;
    int tx = tid & 15, ty = tid >> 4;
    int m0 = blockIdx.x * BM;
    int n0 = blockIdx.y * BN;
    float acc[TM][4];
#pragma unroll
    for (int i = 0; i < TM; ++i)
#pragma unroll
        for (int j = 0; j < 4; ++j) acc[i][j] = 0.f;

    const int NPASS = HAS2 ? 2 : 1;
    for (int pass = 0; pass < NPASS; ++pass) {
        const float* Ap = (HAS2 && pass) ? A2 : A;
        const float* Bp = (HAS2 && pass) ? B2 : B;
        int Kp = (HAS2 && pass) ? K2 : K;
        for (int k0 = 0; k0 < Kp; k0 += BK) {
            // stage A tile (BM x 32), transposed into As[k][m]
#pragma unroll
            for (int r = 0; r < BM/32; ++r) {
                int q = tid + r*256;
                int row = q >> 3, col = (q & 7) << 2;
                float4 v = *(const float4*)&Ap[(size_t)(m0 + row)*Kp + k0 + col];
                As[col+0][row] = v.x; As[col+1][row] = v.y;
                As[col+2][row] = v.z; As[col+3][row] = v.w;
            }
            // stage B tile (32 x 64)
#pragma unroll
            for (int r = 0; r < 2; ++r) {
                int q = tid + r*256;
                int row = q >> 4, col = (q & 15) << 2;
                *(float4*)&Bs[row][col] =
                    *(const float4*)&Bp[(size_t)(k0 + row)*N + n0 + col];
            }
            __syncthreads();
#pragma unroll
            for (int kk = 0; kk < BK; ++kk) {
                float a_[TM], b_[4];
#pragma unroll
                for (int v = 0; v < TM/4; ++v) {
                    float4 t = *(const float4*)&As[kk][ty*TM + 4*v];
                    a_[4*v+0] = t.x; a_[4*v+1] = t.y; a_[4*v+2] = t.z; a_[4*v+3] = t.w;
                }
                float4 tb = *(const float4*)&Bs[kk][tx*4];
                b_[0] = tb.x; b_[1] = tb.y; b_[2] = tb.z; b_[3] = tb.w;
#pragma unroll
                for (int i = 0; i < TM; ++i)
#pragma unroll
                    for (int j = 0; j < 4; ++j)
                        acc[i][j] = fmaf(a_[i], b_[j], acc[i][j]);
            }
            __syncthreads();
        }
    }
    // epilogue
#pragma unroll
    for (int i = 0; i < TM; ++i) {
        int r = m0 + ty*TM + i;
        int c0 = n0 + tx*4;
        float4 v = make_float4(acc[i][0], acc[i][1], acc[i][2], acc[i][3]);
        *(float4*)&C[(size_t)r*N + c0] = v;
        if (WRITE_OUT && ((r & (SEQ-1)) == SEQ-1)) {
            int b = r >> 9;
            *(float4*)&outp[((size_t)(b*OUT_SEQ + iter))*OUT_CH + c0] = v;
        }
    }
}

// ---------------- launch ----------------
extern "C" void kernel_launch(void* const* d_in, const int* in_sizes, int n_in,
                              void* d_out, int out_size, void* d_ws, size_t ws_size,
                              hipStream_t stream) {
    const float* x_in      = (const float*)d_in[0];
    const float* nu_log    = (const float*)d_in[1];
    const float* theta_log = (const float*)d_in[2];
    const float* gamma_log = (const float*)d_in[3];
    const float* B_re      = (const float*)d_in[4];
    const float* B_im      = (const float*)d_in[5];
    const float* C_re      = (const float*)d_in[6];
    const float* C_im      = (const float*)d_in[7];
    const float* D         = (const float*)d_in[8];
    float* out = (float*)d_out;

    float* ws  = (float*)d_ws;
    float* U   = ws + OFF_U;
    float* Z   = ws + OFF_Z;
    float* XA  = ws + OFF_XA;
    float* XB  = ws + OFF_XB;
    float* BgT = ws + OFF_BGT;
    float* Wc  = ws + OFF_WC;
    float* Wd  = ws + OFF_WD;
    float* lam = ws + OFF_LAM;
    float* Hc  = ws + OFF_HC;

    prep_lam_hc<<<1, 384, 0, stream>>>(nu_log, theta_log, lam, Hc);
    prep_bgt<<<(256*768)/256, 256, 0, stream>>>(B_re, B_im, gamma_log, BgT);
    prep_w<<<(768*256 + 256*256)/256, 256, 0, stream>>>(C_re, C_im, D, Wc, Wd);
    copy_x<<<(M_ROWS*256/4)/256, 256, 0, stream>>>(x_in, XA);

    for (int it = 0; it < OUT_SEQ; ++it) {
        const float* Xc = (it & 1) ? XB : XA;
        float*       Xn = (it & 1) ? XA : XB;
        // U = Xc @ BgT   (M=4096, N=768, K=256)
        gemm_f32<128, 8, false, false><<<dim3(M_ROWS/128, 768/64), 256, 0, stream>>>(
            Xc, BgT, 256, nullptr, nullptr, 0, U, 768, nullptr, 0);
        // hs = scan(U)
        scan_k<<<48, 64, 0, stream>>>(U, Z, lam, Hc);
        // Xn = Z @ Wc + Xc @ Wd  (M=4096, N=256), also emit out[:, it, :]
        gemm_f32<64, 4, true, true><<<dim3(M_ROWS/64, 256/64), 256, 0, stream>>>(
            Z, Wc, 768, Xc, Wd, 256, Xn, 256, out, it);
    }
}